// Round 15
// baseline (271.092 us; speedup 1.0000x reference)
//
#include <hip/hip_runtime.h>
#include <hip/hip_bf16.h>

#define NN 100000   // nodes
#define NE 1600000  // edges
#define NG 100      // graphs
#define NPG 1000    // nodes per graph
#define CE 16       // edge channels
#define HH 64       // hidden
#define BN_SCALE 0.99999500003749959f  // 1/sqrt(1+1e-5)
#define NB 512          // edge-chunk blocks
#define ECH (NE / NB)   // 3125 edges per chunk
#define NBIN 400        // dst bins: bin = dst/250 (4 bins per graph)

// LESSON (R3): f32 global atomicAdd on gfx950 = near-memory RMW (~35B HBM each).
// LESSON (R5): int global atomics ~40B each -> counting-sort CSR, no atomics.
// LESSON (R6): edge-per-wave-instruction LDS scatter ~10x slower than
// wave-per-node register accumulation with deep load ILP.
// LESSON (R8): W "register cache" via LDS stays in LDS; use global loads.
// LESSON (R9): un-unrolled load+add loops serialize at L2/L3 latency.
// LESSON (R10): guarded loads (`if(k<hi) v=load`) serialize; clamp+cndmask.
// LESSON (R11/R12): allocator targets 84 VGPR; s_load returns out-of-order so
// scalar streaming can't pipeline. Node GEMMs belong on MFMA.
// LESSON (R13): give every build phase >=2k waves.
// LESSON (R14): message passing is LINEAR -> gather x BEFORE the GEMM
// ((Σx_src)@Wj == Σ(x_src@Wj)); kills the y/z round-trips and folds BN into
// the MFMA epilogue.

typedef __attribute__((ext_vector_type(8))) short bf16x8;
typedef __attribute__((ext_vector_type(4))) float f32x4;
union ABu { bf16x8 f; ushort u[8]; };

__device__ __forceinline__ ushort f2bf_rne(float f) {
  unsigned u = __float_as_uint(f);
  return (ushort)((u + 0x7FFFu + ((u >> 16) & 1u)) >> 16);
}

// ---- phase 1: per-chunk histogram over 400 dst-bins (LDS atomics only) ----
__global__ __launch_bounds__(256) void k_hist(const int* __restrict__ ei,
                                              int* __restrict__ hist) {
  __shared__ int h[NBIN];
  for (int i = threadIdx.x; i < NBIN; i += 256) h[i] = 0;
  __syncthreads();
  int e0 = blockIdx.x * ECH;
  for (int i = threadIdx.x; i < ECH; i += 256) {
    int d = ei[NE + e0 + i];
    atomicAdd(&h[d / 250], 1);
  }
  __syncthreads();
  for (int i = threadIdx.x; i < NBIN; i += 256) hist[blockIdx.x * NBIN + i] = h[i];
}

// ---- phase 2a: per-bin exclusive scan over the 512 chunk-counts ----
__global__ __launch_bounds__(512) void k_scan_a(const int* __restrict__ hist,
                                                int* __restrict__ partial,
                                                int* __restrict__ gtot) {
  __shared__ int sv[512];
  int bin = blockIdx.x, t = threadIdx.x;
  int v = (t < NB) ? hist[t * NBIN + bin] : 0;
  sv[t] = v;
  __syncthreads();
  for (int o = 1; o < 512; o <<= 1) {
    int a = (t >= o) ? sv[t - o] : 0;
    __syncthreads();
    sv[t] += a;
    __syncthreads();
  }
  if (t < NB) partial[t * NBIN + bin] = sv[t] - v;
  if (t == 511) gtot[bin] = sv[511];
}

// ---- phase 2b: exclusive scan of the 400 bin totals -> segment bases ----
__global__ __launch_bounds__(512) void k_scan_b(const int* __restrict__ gtot,
                                                int* __restrict__ gbase) {
  __shared__ int sv[512];
  int t = threadIdx.x;
  int v = (t < NBIN) ? gtot[t] : 0;
  sv[t] = v;
  __syncthreads();
  for (int o = 1; o < 512; o <<= 1) {
    int a = (t >= o) ? sv[t - o] : 0;
    __syncthreads();
    sv[t] += a;
    __syncthreads();
  }
  if (t < NBIN) gbase[t] = sv[t] - v;
  if (t == 511) gbase[NBIN] = sv[511];
}

// ---- phase 3: scatter edges into bin segments (LDS cursors, 1x 8B store) ----
__global__ __launch_bounds__(256) void k_bfill(const int* __restrict__ ei,
                                               const int* __restrict__ partial,
                                               const int* __restrict__ gbase,
                                               unsigned long long* __restrict__ ebuf) {
  __shared__ int cur[NBIN];
  int b = blockIdx.x;
  for (int i = threadIdx.x; i < NBIN; i += 256)
    cur[i] = gbase[i] + partial[b * NBIN + i];
  __syncthreads();
  int e0 = b * ECH;
  for (int i = threadIdx.x; i < ECH; i += 256) {
    int e = e0 + i;
    int d = ei[NE + e], s = ei[e];
    int bin = d / 250;
    int gb = (bin >> 2) * 1000;
    unsigned long long pk = (unsigned long long)(unsigned)e << 32 |
                            (unsigned)((d - gb) << 10) | (unsigned)(s - gb);
    int pos = atomicAdd(&cur[bin], 1);
    ebuf[pos] = pk;
  }
}

// ---- phase 4: within-bin counting sort by node -> per-node CSR (1024 thr) ----
__global__ __launch_bounds__(1024) void k_nsort(
    const unsigned long long* __restrict__ ebuf, const int* __restrict__ gbase,
    unsigned* __restrict__ ebuf2, int* __restrict__ rowptr,
    int* __restrict__ cnt) {
  __shared__ int h[250];
  __shared__ int cur[250];
  __shared__ int sv[256];
  int bin = blockIdx.x, t = threadIdx.x;
  int nb = bin * 250, lbase = (bin & 3) * 250;
  int lo = gbase[bin], hi = gbase[bin + 1];
  if (t < 250) h[t] = 0;
  __syncthreads();
  for (int i = lo + t; i < hi; i += 1024) {
    int dl = (int)((ebuf[i] >> 10) & 1023);
    atomicAdd(&h[dl - lbase], 1);
  }
  __syncthreads();
  int v = (t < 250) ? h[t] : 0;
  if (t < 256) sv[t] = v;
  __syncthreads();
  for (int o = 1; o < 256; o <<= 1) {
    int a = (t < 256 && t >= o) ? sv[t - o] : 0;
    __syncthreads();
    if (t < 256) sv[t] += a;
    __syncthreads();
  }
  if (t < 250) {
    int base = lo + sv[t] - v;  // exclusive
    rowptr[nb + t] = base;
    cur[t] = base;
    cnt[nb + t] = v;
  }
  if (bin == NBIN - 1 && t == 0) rowptr[NN] = hi;
  __syncthreads();
  for (int i = lo + t; i < hi; i += 1024) {
    unsigned long long u = ebuf[i];
    int dl = (int)((u >> 10) & 1023);
    unsigned pk = (unsigned)(u >> 32) << 10 | (unsigned)(u & 1023);
    int pos = atomicAdd(&cur[dl - lbase], 1);
    ebuf2[pos] = pk;
  }
}

// ---- Se: wave-per-node float4 gather; output PACKED BF16 [n][16] ----
#define SEB 25000
__global__ __launch_bounds__(256) void k_se3(const unsigned* __restrict__ ebuf2,
                                             const int* __restrict__ rowptr,
                                             const float* __restrict__ ea,
                                             ushort* __restrict__ Se16) {
  int lane = threadIdx.x & 63;
  int slot = lane >> 2;  // edge slot 0..15
  int q = lane & 3;      // row quarter (4 channels)
  int orig = blockIdx.x;
  int blk = (orig & 7) * (SEB / 8) + (orig >> 3);
  int n0 = blk * 4 + (threadIdx.x >> 6);
  if (n0 >= NN) return;
  int n = __builtin_amdgcn_readfirstlane(n0);
  int lo = rowptr[n], hi = rowptr[n + 1];
  float aA0 = 0.f, aA1 = 0.f, aA2 = 0.f, aA3 = 0.f;
  float aB0 = 0.f, aB1 = 0.f, aB2 = 0.f, aB3 = 0.f;
  for (int k0 = lo; k0 < hi; k0 += 32) {
    int ka = k0 + slot, kb = k0 + 16 + slot;
    int kca = min(ka, NE - 1), kcb = min(kb, NE - 1);
    unsigned eida = ebuf2[kca] >> 10;
    unsigned eidb = ebuf2[kcb] >> 10;
    float4 va = *(const float4*)(ea + (size_t)eida * CE + q * 4);
    float4 vb = *(const float4*)(ea + (size_t)eidb * CE + q * 4);
    bool oka = ka < hi, okb = kb < hi;
    aA0 += oka ? va.x : 0.f;
    aA1 += oka ? va.y : 0.f;
    aA2 += oka ? va.z : 0.f;
    aA3 += oka ? va.w : 0.f;
    aB0 += okb ? vb.x : 0.f;
    aB1 += okb ? vb.y : 0.f;
    aB2 += okb ? vb.z : 0.f;
    aB3 += okb ? vb.w : 0.f;
  }
  float r0 = aA0 + aB0, r1 = aA1 + aB1, r2 = aA2 + aB2, r3 = aA3 + aB3;
#pragma unroll
  for (int o = 4; o < 64; o <<= 1) {
    r0 += __shfl_xor(r0, o);
    r1 += __shfl_xor(r1, o);
    r2 += __shfl_xor(r2, o);
    r3 += __shfl_xor(r3, o);
  }
  if (lane < 4) {
    unsigned lo32 = (unsigned)f2bf_rne(r0) | ((unsigned)f2bf_rne(r1) << 16);
    unsigned hi32 = (unsigned)f2bf_rne(r2) | ((unsigned)f2bf_rne(r3) << 16);
    *(uint2*)(Se16 + (size_t)n * 16 + lane * 4) = make_uint2(lo32, hi32);
  }
}

// ---- per-layer gather on x: Sx[n] = x[n] + sum_{e:dst=n} x[src_e] ----
// 2 nodes per wave (half-wave each); lane = half(1b) x ch-pair(32).
// One 128B coalesced uint row-load instruction covers both channels; 8-deep.
#define GXB 12500  // 4 waves/block, 2 nodes/wave -> 100000 nodes
template <typename T>
__device__ __forceinline__ void ldpair(const T* xg, unsigned srcl, int c,
                                       float& p0, float& p1) {
  if constexpr (sizeof(T) == 4) {
    const float* p = (const float*)xg + (size_t)srcl * HH + 2 * c;
    p0 = p[0];
    p1 = p[1];
  } else {
    unsigned u = *(const unsigned*)((const ushort*)xg + (size_t)srcl * HH + 2 * c);
    p0 = __uint_as_float(u << 16);
    p1 = __uint_as_float(u & 0xffff0000u);
  }
}

template <typename T>
__global__ __launch_bounds__(256) void k_gathx(const T* __restrict__ x,
                                               const unsigned* __restrict__ ebuf2,
                                               const int* __restrict__ rowptr,
                                               ushort* __restrict__ Sx) {
  int lane = threadIdx.x & 63;
  int h = lane >> 5, c = lane & 31;  // half-wave node, channel-pair
  int pr = blockIdx.x * 4 + (threadIdx.x >> 6);
  int n = pr * 2 + h;  // pairs never cross graphs (NPG even)
  int lo = rowptr[n], hi = rowptr[n + 1];
  int deg = hi - lo;
  int gb = (n / NPG) * NPG;
  const T* xg = x + (size_t)gb * HH;
  float a0, a1;
  ldpair(x, (unsigned)n, c, a0, a1);  // self-loop term
  int kend = hi - 1;                  // loop body only runs when deg>0
  for (int k = 0; k < deg; k += 8) {
    int k0 = lo + k;
    int c0 = min(k0 + 0, kend), c1 = min(k0 + 1, kend);
    int c2 = min(k0 + 2, kend), c3 = min(k0 + 3, kend);
    int c4 = min(k0 + 4, kend), c5 = min(k0 + 5, kend);
    int c6 = min(k0 + 6, kend), c7 = min(k0 + 7, kend);
    unsigned s0 = ebuf2[c0] & 1023u, s1 = ebuf2[c1] & 1023u;
    unsigned s2 = ebuf2[c2] & 1023u, s3 = ebuf2[c3] & 1023u;
    unsigned s4 = ebuf2[c4] & 1023u, s5 = ebuf2[c5] & 1023u;
    unsigned s6 = ebuf2[c6] & 1023u, s7 = ebuf2[c7] & 1023u;
    float v00, v01, v10, v11, v20, v21, v30, v31;
    float v40, v41, v50, v51, v60, v61, v70, v71;
    ldpair(xg, s0, c, v00, v01);
    ldpair(xg, s1, c, v10, v11);
    ldpair(xg, s2, c, v20, v21);
    ldpair(xg, s3, c, v30, v31);
    ldpair(xg, s4, c, v40, v41);
    ldpair(xg, s5, c, v50, v51);
    ldpair(xg, s6, c, v60, v61);
    ldpair(xg, s7, c, v70, v71);
    bool o0 = k + 0 < deg, o1 = k + 1 < deg, o2 = k + 2 < deg, o3 = k + 3 < deg;
    bool o4 = k + 4 < deg, o5 = k + 5 < deg, o6 = k + 6 < deg, o7 = k + 7 < deg;
    a0 += (o0 ? v00 : 0.f) + (o1 ? v10 : 0.f) + (o2 ? v20 : 0.f) + (o3 ? v30 : 0.f);
    a1 += (o0 ? v01 : 0.f) + (o1 ? v11 : 0.f) + (o2 ? v21 : 0.f) + (o3 ? v31 : 0.f);
    a0 += (o4 ? v40 : 0.f) + (o5 ? v50 : 0.f) + (o6 ? v60 : 0.f) + (o7 ? v70 : 0.f);
    a1 += (o4 ? v41 : 0.f) + (o5 ? v51 : 0.f) + (o6 ? v61 : 0.f) + (o7 ? v71 : 0.f);
  }
  unsigned w = (unsigned)f2bf_rne(a0) | ((unsigned)f2bf_rne(a1) << 16);
  *(unsigned*)(Sx + (size_t)n * HH + 2 * c) = w;
}

// ---- per-layer fused GEMM+BN via MFMA (R14) ----
// x_next = relu(BN(relu( deg*(x@Wi+b) + Sx@Wj + (Se+1)@We )))
// Layouts (16x16x32): A/B elem e <-> k=(e<4?0:16)+4*(lane>>4)+(e&3);
// C/D col=lane&15, row=(lane>>4)*4+reg.
#define GEMM_TILES (NN / 16)  // 6250
#define GB 512
template <typename T>
__global__ __attribute__((amdgpu_waves_per_eu(2, 4))) __launch_bounds__(256)
void k_gemm2(const T* __restrict__ x, const ushort* __restrict__ Sx,
             const float* __restrict__ W, const float* __restrict__ b,
             const int* __restrict__ cnt, const ushort* __restrict__ Se16,
             const float* __restrict__ gamma, const float* __restrict__ beta,
             ushort* __restrict__ xn, float* __restrict__ embL) {
  int lane = threadIdx.x & 63;
  int g = lane >> 4, r16 = lane & 15;

  ABu Bi[4][2], Bj[4][2], Bs[4];
  float bias4[4], gam4[4], bet4[4];
#pragma unroll
  for (int t = 0; t < 4; ++t) {
    int col = t * 16 + r16;
#pragma unroll
    for (int hh = 0; hh < 2; ++hh)
#pragma unroll
      for (int e = 0; e < 8; ++e) {
        int k = hh * 32 + (e < 4 ? 0 : 16) + 4 * g + (e & 3);
        Bi[t][hh].u[e] = f2bf_rne(W[k * 64 + col]);
        Bj[t][hh].u[e] = f2bf_rne(W[(64 + k) * 64 + col]);
      }
    float ws = 0.f;
#pragma unroll
    for (int m = 0; m < 16; ++m) ws += W[(128 + m) * 64 + col];
#pragma unroll
    for (int e = 0; e < 8; ++e) {
      int k = (e < 4 ? 0 : 16) + 4 * g + (e & 3);
      float v = (k < 16) ? W[(128 + k) * 64 + col] : (k == 16 ? ws : 0.f);
      Bs[t].u[e] = f2bf_rne(v);
    }
    bias4[t] = b[col];
    gam4[t] = gamma[col] * BN_SCALE;
    bet4[t] = beta[col];
  }

  int wid = (blockIdx.x << 2) + (threadIdx.x >> 6);
  int nw = GB * 4;
  for (int tt = wid; tt < GEMM_TILES; tt += nw) {
    int nb = tt * 16;
    ABu A0, A1, X0, X1, AS;
    if constexpr (sizeof(T) == 4) {
      const float* xr = (const float*)x + (size_t)(nb + r16) * HH;
      float4 f0 = *(const float4*)(xr + 4 * g);
      float4 f1 = *(const float4*)(xr + 16 + 4 * g);
      float4 f2 = *(const float4*)(xr + 32 + 4 * g);
      float4 f3 = *(const float4*)(xr + 48 + 4 * g);
      A0.u[0] = f2bf_rne(f0.x); A0.u[1] = f2bf_rne(f0.y);
      A0.u[2] = f2bf_rne(f0.z); A0.u[3] = f2bf_rne(f0.w);
      A0.u[4] = f2bf_rne(f1.x); A0.u[5] = f2bf_rne(f1.y);
      A0.u[6] = f2bf_rne(f1.z); A0.u[7] = f2bf_rne(f1.w);
      A1.u[0] = f2bf_rne(f2.x); A1.u[1] = f2bf_rne(f2.y);
      A1.u[2] = f2bf_rne(f2.z); A1.u[3] = f2bf_rne(f2.w);
      A1.u[4] = f2bf_rne(f3.x); A1.u[5] = f2bf_rne(f3.y);
      A1.u[6] = f2bf_rne(f3.z); A1.u[7] = f2bf_rne(f3.w);
    } else {
      const ushort* xr = (const ushort*)x + (size_t)(nb + r16) * HH;
      *(ushort4*)&A0.u[0] = *(const ushort4*)(xr + 4 * g);
      *(ushort4*)&A0.u[4] = *(const ushort4*)(xr + 16 + 4 * g);
      *(ushort4*)&A1.u[0] = *(const ushort4*)(xr + 32 + 4 * g);
      *(ushort4*)&A1.u[4] = *(const ushort4*)(xr + 48 + 4 * g);
    }
    const ushort* sxr = Sx + (size_t)(nb + r16) * HH;
    *(ushort4*)&X0.u[0] = *(const ushort4*)(sxr + 4 * g);
    *(ushort4*)&X0.u[4] = *(const ushort4*)(sxr + 16 + 4 * g);
    *(ushort4*)&X1.u[0] = *(const ushort4*)(sxr + 32 + 4 * g);
    *(ushort4*)&X1.u[4] = *(const ushort4*)(sxr + 48 + 4 * g);
    const ushort* sr = Se16 + (size_t)(nb + r16) * 16;
    *(ushort4*)&AS.u[0] = *(const ushort4*)(sr + 4 * g);
    AS.u[4] = (g == 0) ? (ushort)0x3F80 : (ushort)0;  // k==16 -> 1.0
    AS.u[5] = 0; AS.u[6] = 0; AS.u[7] = 0;
    float dq[4];
#pragma unroll
    for (int q = 0; q < 4; ++q) dq[q] = (float)(cnt[nb + 4 * g + q] + 1);

    f32x4 accI[4], accR[4];
#pragma unroll
    for (int t = 0; t < 4; ++t) {
      f32x4 zz = {0.f, 0.f, 0.f, 0.f};
      zz = __builtin_amdgcn_mfma_f32_16x16x32_bf16(A0.f, Bi[t][0].f, zz, 0, 0, 0);
      accI[t] = __builtin_amdgcn_mfma_f32_16x16x32_bf16(A1.f, Bi[t][1].f, zz, 0, 0, 0);
      f32x4 rr = {0.f, 0.f, 0.f, 0.f};
      rr = __builtin_amdgcn_mfma_f32_16x16x32_bf16(X0.f, Bj[t][0].f, rr, 0, 0, 0);
      rr = __builtin_amdgcn_mfma_f32_16x16x32_bf16(X1.f, Bj[t][1].f, rr, 0, 0, 0);
      accR[t] = __builtin_amdgcn_mfma_f32_16x16x32_bf16(AS.f, Bs[t].f, rr, 0, 0, 0);
    }
#pragma unroll
    for (int q = 0; q < 4; ++q) {
      int node = nb + 4 * g + q;
      ushort* xp = xn + (size_t)node * 64 + r16;
      bool spec = (node % NPG) == 0;
#pragma unroll
      for (int t = 0; t < 4; ++t) {
        float zv = dq[q] * (accI[t][q] + bias4[t]) + accR[t][q];
        zv = fmaxf(zv, 0.f);
        zv = gam4[t] * zv + bet4[t];
        zv = fmaxf(zv, 0.f);
        xp[t * 16] = f2bf_rne(zv);
        if (spec) embL[(node / NPG) * HH + t * 16 + r16] = zv;
      }
    }
  }
}

// ---- pool: 400 blocks x 8 waves, 4-deep unrolled; partial[bin][64] f32 ----
__global__ __launch_bounds__(512) void k_pool(const __hip_bfloat16* __restrict__ xf,
                                              float* __restrict__ partial) {
  __shared__ float pp[8][64];
  int bin = blockIdx.x;
  int lane = threadIdx.x & 63, wv = threadIdx.x >> 6;
  const __hip_bfloat16* base = xf + (size_t)bin * 250 * HH;
  float acc = 0.f;
  int i = wv;
  for (; i + 24 < 250; i += 32) {
    float v0 = __bfloat162float(base[(size_t)i * HH + lane]);
    float v1 = __bfloat162float(base[(size_t)(i + 8) * HH + lane]);
    float v2 = __bfloat162float(base[(size_t)(i + 16) * HH + lane]);
    float v3 = __bfloat162float(base[(size_t)(i + 24) * HH + lane]);
    acc += (v0 + v1) + (v2 + v3);
  }
  for (; i < 250; i += 8) acc += __bfloat162float(base[(size_t)i * HH + lane]);
  pp[wv][lane] = acc;
  __syncthreads();
  if (wv == 0) {
    float s = ((pp[0][lane] + pp[1][lane]) + (pp[2][lane] + pp[3][lane])) +
              ((pp[4][lane] + pp[5][lane]) + (pp[6][lane] + pp[7][lane]));
    partial[bin * 64 + lane] = s;
  }
}

// ---------------- readout MLP: ILP-unrolled fc1, parallel fc2 ----------------
__global__ __launch_bounds__(256) void k_final(
    const float* __restrict__ partial, const float* __restrict__ emb,
    const float* __restrict__ nbr, const float* __restrict__ fc1w,
    const float* __restrict__ fc1b, const float* __restrict__ fc2w,
    const float* __restrict__ fc2b, float* __restrict__ out) {
  __shared__ float feats[320];
  __shared__ float r1[256];
  __shared__ float red[4][4];
  int g = blockIdx.x;
  int t = threadIdx.x;
  if (t < 64) {
    const float* pb = partial + 4 * g * 64;
    feats[t] = (pb[t] + pb[64 + t]) + (pb[128 + t] + pb[192 + t]);
    feats[256 + t] = nbr[(size_t)g * HH + t];
  } else {
    int j = t - 64;
    feats[64 + j] = emb[((size_t)(j >> 6) * NG + g) * HH + (j & 63)];
  }
  __syncthreads();
  float a0 = fc1b[t], a1 = 0.f, a2 = 0.f, a3 = 0.f;
  const float* wp = fc1w + t;
  for (int k = 0; k < 320; k += 8) {
    float w0 = wp[(k + 0) * 256], w1 = wp[(k + 1) * 256];
    float w2 = wp[(k + 2) * 256], w3 = wp[(k + 3) * 256];
    float w4 = wp[(k + 4) * 256], w5 = wp[(k + 5) * 256];
    float w6 = wp[(k + 6) * 256], w7 = wp[(k + 7) * 256];
    a0 = fmaf(feats[k], w0, a0);
    a1 = fmaf(feats[k + 1], w1, a1);
    a2 = fmaf(feats[k + 2], w2, a2);
    a3 = fmaf(feats[k + 3], w3, a3);
    a0 = fmaf(feats[k + 4], w4, a0);
    a1 = fmaf(feats[k + 5], w5, a1);
    a2 = fmaf(feats[k + 6], w6, a2);
    a3 = fmaf(feats[k + 7], w7, a3);
  }
  float rv = fmaxf((a0 + a1) + (a2 + a3), 0.f);
  r1[t] = rv;
  float p0 = rv * fc2w[t * 4 + 0];
  float p1 = rv * fc2w[t * 4 + 1];
  float p2 = rv * fc2w[t * 4 + 2];
  float p3 = rv * fc2w[t * 4 + 3];
#pragma unroll
  for (int o = 1; o < 64; o <<= 1) {
    p0 += __shfl_xor(p0, o);
    p1 += __shfl_xor(p1, o);
    p2 += __shfl_xor(p2, o);
    p3 += __shfl_xor(p3, o);
  }
  if ((t & 63) == 0) {
    int wv = t >> 6;
    red[wv][0] = p0; red[wv][1] = p1; red[wv][2] = p2; red[wv][3] = p3;
  }
  __syncthreads();
  if (t < 4)
    out[g * 4 + t] = fc2b[t] +
                     ((red[0][t] + red[1][t]) + (red[2][t] + red[3][t]));
}

extern "C" void kernel_launch(void* const* d_in, const int* in_sizes, int n_in,
                              void* d_out, int out_size, void* d_ws, size_t ws_size,
                              hipStream_t stream) {
  const float* x     = (const float*)d_in[0];
  const float* eattr = (const float*)d_in[1];
  const float* nbr   = (const float*)d_in[2];
  const float* W     = (const float*)d_in[3];
  const float* b     = (const float*)d_in[4];
  const float* gamma = (const float*)d_in[5];
  const float* beta  = (const float*)d_in[6];
  const float* fc1w  = (const float*)d_in[7];
  const float* fc1b  = (const float*)d_in[8];
  const float* fc2w  = (const float*)d_in[9];
  const float* fc2b  = (const float*)d_in[10];
  const int*   ei    = (const int*)d_in[11];
  float* out = (float*)d_out;
  (void)in_sizes; (void)n_in; (void)out_size; (void)ws_size;

  char* p = (char*)d_ws;
  size_t off = 0;
  auto alloc = [&](size_t bytes) {
    char* q = p + off;
    off += (bytes + 255) & ~(size_t)255;
    return q;
  };
  int* hist    = (int*)alloc((size_t)NB * NBIN * 4);
  int* partial = (int*)alloc((size_t)NB * NBIN * 4);
  int* gtot    = (int*)alloc((size_t)NBIN * 4);
  int* gbase   = (int*)alloc((size_t)(NBIN + 1) * 4);
  unsigned long long* ebuf = (unsigned long long*)alloc((size_t)NE * 8);
  unsigned* ebuf2 = (unsigned*)alloc((size_t)NE * 4);
  int* rowptr  = (int*)alloc((size_t)(NN + 1) * 4);
  ushort* Se16 = (ushort*)alloc((size_t)NN * 16 * 2);
  int*   cnt   = (int*)alloc((size_t)NN * 4);
  ushort* Sx   = (ushort*)alloc((size_t)NN * HH * 2);
  ushort* xA   = (ushort*)alloc((size_t)NN * HH * 2);
  ushort* xB   = (ushort*)alloc((size_t)NN * HH * 2);
  float* emb   = (float*)alloc((size_t)3 * NG * HH * 4);
  float* pool  = (float*)alloc((size_t)NBIN * HH * 4);

  // CSR build via two-level counting sort (zero global atomics, no memsets)
  k_hist<<<NB, 256, 0, stream>>>(ei, hist);
  k_scan_a<<<NBIN, 512, 0, stream>>>(hist, partial, gtot);
  k_scan_b<<<1, 512, 0, stream>>>(gtot, gbase);
  k_bfill<<<NB, 256, 0, stream>>>(ei, partial, gbase, ebuf);
  k_nsort<<<NBIN, 1024, 0, stream>>>(ebuf, gbase, ebuf2, rowptr, cnt);
  k_se3<<<SEB, 256, 0, stream>>>(ebuf2, rowptr, eattr, Se16);

  // layer 0: x (f32) -> xA
  k_gathx<float><<<GXB, 256, 0, stream>>>(x, ebuf2, rowptr, Sx);
  k_gemm2<float><<<GB, 256, 0, stream>>>(x, Sx, W, b, cnt, Se16, gamma, beta,
                                         xA, emb);
  // layer 1: xA -> xB
  k_gathx<ushort><<<GXB, 256, 0, stream>>>(xA, ebuf2, rowptr, Sx);
  k_gemm2<ushort><<<GB, 256, 0, stream>>>(xA, Sx, W + 144 * 64, b + 64, cnt, Se16,
                                          gamma + 64, beta + 64, xB, emb + NG * HH);
  // layer 2: xB -> xA
  k_gathx<ushort><<<GXB, 256, 0, stream>>>(xB, ebuf2, rowptr, Sx);
  k_gemm2<ushort><<<GB, 256, 0, stream>>>(xB, Sx, W + 2 * 144 * 64, b + 128, cnt,
                                          Se16, gamma + 128, beta + 128, xA,
                                          emb + 2 * NG * HH);

  k_pool<<<NBIN, 512, 0, stream>>>((const __hip_bfloat16*)xA, pool);
  k_final<<<NG, 256, 0, stream>>>(pool, emb, nbr, fc1w, fc1b, fc2w, fc2b, out);
}